// Round 13
// baseline (5788.938 us; speedup 1.0000x reference)
//
#include <hip/hip_runtime.h>
#include <hip/hip_bf16.h>
#include <math.h>

#define LAY 20
#define HID 512
#define NH 8
#define DH 64
#define OUTC 1000
#define SEQ 197
#define SPAD 224
#define BATCH 64
#define TT (BATCH*SEQ)      /* 12608 tokens */
#define M2 12800            /* 100*128 */
#define NPTOK (BATCH*196)   /* 12544 */
#define IN_DIM 768

typedef __attribute__((ext_vector_type(8))) short bf16x8;
typedef __attribute__((ext_vector_type(4))) float f32x4;

__device__ __forceinline__ ushort f2bf(float f){
  __hip_bfloat16 h = __float2bfloat16(f);
  return *(ushort*)&h;
}
__device__ __forceinline__ float bf2f(ushort u){
  __hip_bfloat16 h = *(__hip_bfloat16*)&u;
  return __bfloat162float(h);
}

__device__ __forceinline__ float posemb(int i, int j){
  float je = (float)(j & ~1);
  float ang = (float)i * powf(10000.0f, -je * (1.0f/(float)HID));
  return (j & 1) ? cosf(ang) : sinf(ang);
}

__device__ __forceinline__ float gelu_exact(float x){
  return 0.5f * x * (1.0f + erff(x * 0.70710678118654752f));
}

__device__ __forceinline__ void gld_lds16(const ushort* g, ushort* l){
  __builtin_amdgcn_global_load_lds((const __attribute__((address_space(1))) void*)g,
                                   (__attribute__((address_space(3))) void*)l, 16, 0, 0);
}

// ------- pos embedding table [SEQ][HID] -------
__global__ __launch_bounds__(512)
void pos_kernel(float* __restrict__ pos){
  int i = blockIdx.x, j = threadIdx.x;
  pos[(size_t)i*HID + j] = posemb(i, j);
}

// ------- weight convert+transpose: src fp32 [R][C] -> dst bf16 [C][R] -------
__global__ __launch_bounds__(256)
void convt_kernel(const float* __restrict__ src, ushort* __restrict__ dst,
                  int R, int C){
  __shared__ float tile[32][33];
  const float* s = src + (size_t)blockIdx.z * R * C;
  ushort* d      = dst + (size_t)blockIdx.z * R * C;
  int r0 = blockIdx.y * 32, c0 = blockIdx.x * 32;
  int tc = threadIdx.x & 31, tr = threadIdx.x >> 5;
  #pragma unroll
  for (int i = 0; i < 4; ++i)
    tile[tr + i*8][tc] = s[(size_t)(r0 + tr + i*8)*C + c0 + tc];
  __syncthreads();
  #pragma unroll
  for (int i = 0; i < 4; ++i)
    d[(size_t)(c0 + tr + i*8)*R + r0 + tc] = f2bf(tile[tc][tr + i*8]);
}

// ------- elementwise fp32 -> bf16 convert -------
__global__ __launch_bounds__(256)
void cvt_kernel(const float* __restrict__ src, ushort* __restrict__ dst, int count){
  int idx = blockIdx.x * 256 + threadIdx.x;
  if (idx < count) dst[idx] = f2bf(src[idx]);
}

// ---------------- patchify ----------------
__global__ __launch_bounds__(256)
void patchify_kernel(const float* __restrict__ x, ushort* __restrict__ p){
  int idx = blockIdx.x * 256 + threadIdx.x;
  int r   = idx / 768, cdx = idx - r * 768;
  int n   = r / 196,  pp  = r - n * 196;
  int pr  = pp / 14,  pc  = pp - pr * 14;
  int c   = cdx >> 8, rem = cdx & 255;
  int ph  = rem >> 4, pw  = rem & 15;
  p[idx] = f2bf(x[ (((size_t)(n*3 + c)*224) + pr*16 + ph)*224 + pc*16 + pw ]);
}

// ---------------- cls row ----------------
__global__ __launch_bounds__(512)
void cls_kernel(const float* __restrict__ cls, const float* __restrict__ pos,
                float* __restrict__ h){
  int n = blockIdx.x, e = threadIdx.x;
  h[(size_t)n*SEQ*HID + e] = cls[e] + pos[e];
}

// ---------------- pipelined MFMA GEMM, 128xBN tile, BK=32, 5 blk/CU -------
// 256 threads (4 waves 2x2), double-buffered LDS (A 8KB + B BN*64 per buf).
// Slot-XOR swizzle slot^=((row>>1)&3) both sides. Counted vmcnt. Cross-block
// overlap hides barrier stalls (round-11/12 proven lever).
// EPI: 1 = bias+GELU -> bf16; 2 = bias + add into fp32 C rows<Mreal;
//      3 = embed: bias + pos add, scatter rows (rows<Mreal), fp32.
template<int BN, int EPI>
__global__ __launch_bounds__(256, 5)
void gemm_pipe(const ushort* __restrict__ A, const ushort* __restrict__ Bt,
               const float* __restrict__ bias, void* __restrict__ Cv,
               int K, int N, int Mreal, int NBX, const float* __restrict__ pos){
  constexpr int BM = 128;
  constexpr int MF = 4, NF = BN/32;  // per-wave 64 x (NF*16) region
  constexpr int BQ = BN/64;          // B staging issues per thread
  constexpr int TBS = 8192 + BN*64;  // bytes per buffer
  constexpr int ES = NF*16 + 12;     // epilogue staging stride (floats)
  __shared__ char lds[2*TBS];

  int t = threadIdx.x, lane = t & 63, wave = t >> 6;
  int wr = wave >> 1, wn = wave & 1;
  int l16 = lane & 15, g = lane >> 4;

  // bijective XCD-aware block swizzle
  int NB = gridDim.x;
  int q8 = NB >> 3, r8 = NB & 7;
  int xcd = blockIdx.x & 7, i8 = blockIdx.x >> 3;
  int swz = (xcd < r8 ? xcd*(q8+1) : r8*(q8+1) + (xcd-r8)*q8) + i8;
  int rb = (swz / NBX) * BM, cb = (swz % NBX) * BN;

  // staging: thread t -> row (t>>2) within a 64-row group; pre-swizzled
  // global 16B chunk (t&3)^((row>>1)&3); LDS dest linear.
  const int srow = t >> 2;
  const int kel  = ((t & 3) ^ ((srow >> 1) & 3)) * 8;
  const ushort* pA[2]; const ushort* pB[BQ];
  #pragma unroll
  for (int q = 0; q < 2; ++q)
    pA[q] = A + (size_t)(rb + q*64 + srow)*K + kel;
  #pragma unroll
  for (int q = 0; q < BQ; ++q)
    pB[q] = Bt + (size_t)(cb + q*64 + srow)*K + kel;
  const int sdst = t*16;

  // ds_read offsets with matching slot-XOR ((row>>1)&3 == (l16>>1)&3)
  const int sx = (l16 >> 1) & 3;
  int aoff[MF], boff[NF];
  #pragma unroll
  for (int mf = 0; mf < MF; ++mf)
    aoff[mf] = (wr*64 + mf*16 + l16)*64 + ((g ^ sx) << 4);
  #pragma unroll
  for (int nf = 0; nf < NF; ++nf)
    boff[nf] = 8192 + (wn*(NF*16) + nf*16 + l16)*64 + ((g ^ sx) << 4);

  f32x4 acc[MF][NF];
  #pragma unroll
  for (int mf = 0; mf < MF; ++mf)
    #pragma unroll
    for (int nf = 0; nf < NF; ++nf)
      acc[mf][nf] = (f32x4){0.f,0.f,0.f,0.f};

  // prologue: stage tile 0 into buffer 0
  #pragma unroll
  for (int q = 0; q < 2; ++q)
    gld_lds16(pA[q], (ushort*)(lds + q*4096 + sdst));
  #pragma unroll
  for (int q = 0; q < BQ; ++q)
    gld_lds16(pB[q], (ushort*)(lds + 8192 + q*4096 + sdst));

  int NT = K / 32;
  for (int tt = 0; tt < NT; ++tt){
    const char* cur = lds + (tt & 1)*TBS;
    char* nxt = lds + ((tt & 1) ^ 1)*TBS;
    bool pf = (tt + 1 < NT);
    if (pf){
      const size_t kb = (size_t)(tt + 1) * 32;
      #pragma unroll
      for (int q = 0; q < 2; ++q)
        gld_lds16(pA[q] + kb, (ushort*)(nxt + q*4096 + sdst));
      #pragma unroll
      for (int q = 0; q < BQ; ++q)
        gld_lds16(pB[q] + kb, (ushort*)(nxt + 8192 + q*4096 + sdst));
      if constexpr (BQ == 2)
        asm volatile("s_waitcnt vmcnt(4)" ::: "memory");
      else
        asm volatile("s_waitcnt vmcnt(3)" ::: "memory");
    } else {
      asm volatile("s_waitcnt vmcnt(0)" ::: "memory");
    }
    __builtin_amdgcn_s_barrier();   // tile tt data visible

    bf16x8 af[MF], bfr[NF];
    #pragma unroll
    for (int nf = 0; nf < NF; ++nf)
      bfr[nf] = *(const bf16x8*)(cur + boff[nf]);
    #pragma unroll
    for (int mf = 0; mf < MF; ++mf)
      af[mf] = *(const bf16x8*)(cur + aoff[mf]);

    __builtin_amdgcn_s_setprio(1);
    #pragma unroll
    for (int mf = 0; mf < MF; ++mf)
      #pragma unroll
      for (int nf = 0; nf < NF; ++nf)
        acc[mf][nf] = __builtin_amdgcn_mfma_f32_16x16x32_bf16(af[mf], bfr[nf], acc[mf][nf], 0, 0, 0);
    __builtin_amdgcn_s_setprio(0);
    __builtin_amdgcn_s_barrier();   // all waves done reading cur
  }

  // -------- coalesced epilogue via per-wave LDS transpose (static idx) --
  float bvv[NF];
  #pragma unroll
  for (int nf = 0; nf < NF; ++nf)
    bvv[nf] = bias[cb + wn*(NF*16) + nf*16 + l16];
  float* eps = (float*)(lds + wave*(16*ES*4));

  #pragma unroll
  for (int mf = 0; mf < MF; ++mf){
    #pragma unroll
    for (int nf = 0; nf < NF; ++nf)
      #pragma unroll
      for (int j = 0; j < 4; ++j){
        float val = acc[mf][nf][j] + bvv[nf];
        if (EPI == 1) val = gelu_exact(val);
        eps[(g*4+j)*ES + nf*16 + l16] = val;
      }
    #pragma unroll
    for (int i = 0; i < NF; ++i){
      int id = i*64 + lane;
      int r = id / (4*NF), c4 = id % (4*NF);
      float4 vv = *(float4*)&eps[r*ES + c4*4];
      int grow = rb + wr*64 + mf*16 + r;
      int gcol = cb + wn*(NF*16) + c4*4;
      if (EPI == 1){
        ushort4 u;
        u.x = f2bf(vv.x); u.y = f2bf(vv.y); u.z = f2bf(vv.z); u.w = f2bf(vv.w);
        *(ushort4*)&((ushort*)Cv)[(size_t)grow*N + gcol] = u;
      } else if (EPI == 2){
        if (grow < Mreal){
          float* cp = &((float*)Cv)[(size_t)grow*N + gcol];
          float4 o = *(float4*)cp;
          o.x += vv.x; o.y += vv.y; o.z += vv.z; o.w += vv.w;
          *(float4*)cp = o;
        }
      } else { // EPI == 3
        if (grow < Mreal){
          int bn = grow / 196, sp = grow - bn*196;
          float4 pv = *(const float4*)&pos[(size_t)(1+sp)*HID + gcol];
          vv.x += pv.x; vv.y += pv.y; vv.z += pv.z; vv.w += pv.w;
          *(float4*)&((float*)Cv)[((size_t)bn*SEQ + 1 + sp)*HID + gcol] = vv;
        }
      }
    }
  }
}

// ---------------- LayerNorm (fp32 in, bf16 out) ----------------
__global__ __launch_bounds__(256)
void ln_kernel(const float* __restrict__ x, const float* __restrict__ g,
               const float* __restrict__ b, ushort* __restrict__ y){
  int tok = blockIdx.x, t = threadIdx.x;
  const float* xp = x + (size_t)tok*HID;
  float v1 = xp[t], v2 = xp[t + 256];
  __shared__ float red[4];
  float s = v1 + v2;
  #pragma unroll
  for (int off = 32; off; off >>= 1) s += __shfl_xor(s, off);
  if ((t & 63) == 0) red[t >> 6] = s;
  __syncthreads();
  float mean = (red[0] + red[1] + red[2] + red[3]) * (1.0f/512.0f);
  __syncthreads();
  float d1 = v1 - mean, d2 = v2 - mean;
  s = d1*d1 + d2*d2;
  #pragma unroll
  for (int off = 32; off; off >>= 1) s += __shfl_xor(s, off);
  if ((t & 63) == 0) red[t >> 6] = s;
  __syncthreads();
  float var = (red[0] + red[1] + red[2] + red[3]) * (1.0f/512.0f);
  float rs  = rsqrtf(var + 1e-5f);
  ushort* yp = y + (size_t)tok*HID;
  yp[t]       = f2bf(d1*rs*g[t]       + b[t]);
  yp[t + 256] = f2bf(d2*rs*g[t + 256] + b[t + 256]);
}

// ---------------- MFMA QKV projection, coalesced row-major outputs -------
__global__ __launch_bounds__(256)
void qkv_mfma(const ushort* __restrict__ y,
              const ushort* __restrict__ wqb, const ushort* __restrict__ wkb,
              const ushort* __restrict__ wvb,
              const float* __restrict__ bq, const float* __restrict__ bk,
              const float* __restrict__ bv,
              ushort* __restrict__ q, ushort* __restrict__ k,
              ushort* __restrict__ v){
  __shared__ short As[128*64];
  __shared__ short Bs[64*64];
  int t = threadIdx.x;
  int lane = t & 63, wave = t >> 6;
  int l16 = lane & 15, g = lane >> 4;
  int p  = blockIdx.y >> 3, hh = blockIdx.y & 7;
  int rb = blockIdx.x * 128;

  const ushort* W; const float* bias; ushort* out;
  if (p == 0)      { W = wqb; bias = bq; out = q; }
  else if (p == 1) { W = wkb; bias = bk; out = k; }
  else             { W = wvb; bias = bv; out = v; }
  W    += (size_t)hh * 64 * 64;
  bias += hh * 64;

  int srow = t >> 3, skoff = (t & 7) * 8;
  const ushort* Ab = y + (size_t)(rb + srow)*HID + hh*64 + skoff;
  const ushort* Bb = W + (size_t)srow*64 + skoff;
  #pragma unroll
  for (int i = 0; i < 4; ++i)
    gld_lds16(Ab + (size_t)(i*32)*HID, (ushort*)&As[t*8 + i*2048]);
  #pragma unroll
  for (int i = 0; i < 2; ++i)
    gld_lds16(Bb + (size_t)(i*32)*64, (ushort*)&Bs[t*8 + i*2048]);
  __syncthreads();

  f32x4 acc[2][4];
  #pragma unroll
  for (int m = 0; m < 2; ++m)
    #pragma unroll
    for (int n = 0; n < 4; ++n)
      acc[m][n] = (f32x4){0.f,0.f,0.f,0.f};

  #pragma unroll
  for (int kc = 0; kc < 2; ++kc){
    bf16x8 af[2], bfr[4];
    #pragma unroll
    for (int m = 0; m < 2; ++m)
      af[m] = *(bf16x8*)&As[(wave*32 + m*16 + l16)*64 + kc*32 + g*8];
    #pragma unroll
    for (int n = 0; n < 4; ++n)
      bfr[n] = *(bf16x8*)&Bs[(n*16 + l16)*64 + kc*32 + g*8];
    #pragma unroll
    for (int m = 0; m < 2; ++m)
      #pragma unroll
      for (int n = 0; n < 4; ++n)
        acc[m][n] = __builtin_amdgcn_mfma_f32_16x16x32_bf16(af[m], bfr[n], acc[m][n], 0, 0, 0);
  }
  __syncthreads();   // reuse As for epilogue staging

  float bvv[4];
  #pragma unroll
  for (int nd = 0; nd < 4; ++nd) bvv[nd] = bias[nd*16 + l16];
  ushort* eps = (ushort*)As + wave*(16*72);
  #pragma unroll
  for (int mch = 0; mch < 2; ++mch){
    #pragma unroll
    for (int nd = 0; nd < 4; ++nd)
      #pragma unroll
      for (int j = 0; j < 4; ++j)
        eps[(g*4+j)*72 + nd*16 + l16] = f2bf(acc[mch][nd][j] + bvv[nd]);
    #pragma unroll
    for (int i = 0; i < 2; ++i){
      int id = i*64 + lane;
      int r = id >> 3, c8 = id & 7;
      uint4 vv = *(uint4*)&eps[r*72 + c8*8];
      int tok = rb + wave*32 + mch*16 + r;
      if (tok < TT)
        *(uint4*)&out[(size_t)tok*HID + hh*64 + c8*8] = vv;
    }
  }
}

// ---------------- MFMA flash attention + residual add into h ----------------
__global__ __launch_bounds__(512, 4)
void attn_kernel(const ushort* __restrict__ q, const ushort* __restrict__ k,
                 const ushort* __restrict__ v, float* __restrict__ h){
  __shared__ ushort Ks[SPAD*64];
  __shared__ ushort Vs[64*256];
  __shared__ ushort Ps[8][32*40];
  int nh = blockIdx.x;
  int n = nh >> 3, hd = nh & 7;
  int t = threadIdx.x;
  int lane = t & 63, wave = t >> 6;
  int l16 = lane & 15, g = lane >> 4;

  const ushort* kbase = k + ((size_t)n*SEQ)*HID + hd*64;
  for (int c = t; c < 224*8; c += 512){
    int s = c >> 3, c8 = (c & 7) * 8;
    int sr = s < SEQ ? s : SEQ-1;
    uint4 val = *(const uint4*)&kbase[(size_t)sr*HID + c8];
    int byte = s*128 + c8*2;
    byte ^= (s & 7) << 4;
    *(uint4*)((char*)Ks + byte) = val;
  }
  const ushort* vbase = v + ((size_t)n*SEQ)*HID + hd*64;
  for (int c = t; c < 224*8; c += 512){
    int s = c >> 3, d8 = (c & 7) * 8;
    uint4 val = {0u,0u,0u,0u};
    if (s < SEQ) val = *(const uint4*)&vbase[(size_t)s*HID + d8];
    ushort* vsp = (ushort*)Vs;
    #pragma unroll
    for (int e = 0; e < 8; ++e){
      int d = d8 + e;
      int swzi = ((d & 7) ^ ((d >> 3) & 7)) << 4;
      int byte = d*512 + ((s*2) ^ swzi);
      vsp[byte >> 1] = ((ushort*)&val)[e];
    }
  }

  int qrow0 = wave * 32;
  bool wactive = qrow0 < SEQ;
  bf16x8 aq[2][2];
  if (wactive){
    #pragma unroll
    for (int m = 0; m < 2; ++m){
      int row = qrow0 + m*16 + l16;
      int sr = row < SEQ ? row : SEQ-1;
      const ushort* qp = q + ((size_t)n*SEQ + sr)*HID + hd*64;
      #pragma unroll
      for (int kc = 0; kc < 2; ++kc)
        aq[m][kc] = *(const bf16x8*)&qp[kc*32 + g*8];
    }
  }
  __syncthreads();

  if (wactive){
    ushort* myP = &Ps[wave][0];
    f32x4 accO[2][4];
    float mrun[2][4], lrun[2][4];
    #pragma unroll
    for (int m = 0; m < 2; ++m){
      #pragma unroll
      for (int nd = 0; nd < 4; ++nd) accO[m][nd] = (f32x4){0.f,0.f,0.f,0.f};
      #pragma unroll
      for (int j = 0; j < 4; ++j){ mrun[m][j] = -1e30f; lrun[m][j] = 0.f; }
    }

    for (int kt = 0; kt < 7; ++kt){
      f32x4 accS[2][2];
      #pragma unroll
      for (int m = 0; m < 2; ++m)
        #pragma unroll
        for (int nn = 0; nn < 2; ++nn) accS[m][nn] = (f32x4){0.f,0.f,0.f,0.f};
      #pragma unroll
      for (int kc = 0; kc < 2; ++kc){
        bf16x8 bk[2];
        #pragma unroll
        for (int nn = 0; nn < 2; ++nn){
          int srow = kt*32 + nn*16 + l16;
          int byte = srow*128 + kc*64 + g*16;
          byte ^= (srow & 7) << 4;
          bk[nn] = *(const bf16x8*)((const char*)Ks + byte);
        }
        #pragma unroll
        for (int m = 0; m < 2; ++m)
          #pragma unroll
          for (int nn = 0; nn < 2; ++nn)
            accS[m][nn] = __builtin_amdgcn_mfma_f32_16x16x32_bf16(aq[m][kc], bk[nn], accS[m][nn], 0, 0, 0);
      }
      bool kv0 = (kt*32 + l16) < SEQ;
      bool kv1 = (kt*32 + 16 + l16) < SEQ;
      #pragma unroll
      for (int m = 0; m < 2; ++m){
        #pragma unroll
        for (int j = 0; j < 4; ++j){
          float s0 = kv0 ? accS[m][0][j]*0.125f : -1e30f;
          float s1 = kv1 ? accS[m][1][j]*0.125f : -1e30f;
          float mx = fmaxf(s0, s1);
          mx = fmaxf(mx, __shfl_xor(mx, 1));
          mx = fmaxf(mx, __shfl_xor(mx, 2));
          mx = fmaxf(mx, __shfl_xor(mx, 4));
          mx = fmaxf(mx, __shfl_xor(mx, 8));
          float mold = mrun[m][j];
          float mnew = fmaxf(mold, mx);
          float corr = __expf(mold - mnew);
          mrun[m][j] = mnew;
          float p0 = __expf(s0 - mnew);
          float p1 = __expf(s1 - mnew);
          float rs = p0 + p1;
          rs += __shfl_xor(rs, 1);
          rs += __shfl_xor(rs, 2);
          rs += __shfl_xor(rs, 4);
          rs += __shfl_xor(rs, 8);
          lrun[m][j] = lrun[m][j]*corr + rs;
          #pragma unroll
          for (int nd = 0; nd < 4; ++nd) accO[m][nd][j] *= corr;
          int prow = m*16 + g*4 + j;
          myP[prow*40 + l16]      = f2bf(p0);
          myP[prow*40 + 16 + l16] = f2bf(p1);
        }
      }
      bf16x8 ap[2], bv[4];
      #pragma unroll
      for (int m = 0; m < 2; ++m)
        ap[m] = *(const bf16x8*)&myP[(m*16 + l16)*40 + g*8];
      #pragma unroll
      for (int nd = 0; nd < 4; ++nd){
        int d = nd*16 + l16;
        int byte = d*512 + kt*64 + g*16;
        byte ^= ((d & 7) ^ ((d >> 3) & 7)) << 4;
        bv[nd] = *(const bf16x8*)((const char*)Vs + byte);
      }
      #pragma unroll
      for (int m = 0; m < 2; ++m)
        #pragma unroll
        for (int nd = 0; nd < 4; ++nd)
          accO[m][nd] = __builtin_amdgcn_mfma_f32_16x16x32_bf16(ap[m], bv[nd], accO[m][nd], 0, 0, 0);
    }

    #pragma unroll
    for (int m = 0; m < 2; ++m){
      #pragma unroll
      for (int j = 0; j < 4; ++j){
        int row = qrow0 + m*16 + g*4 + j;
        if (row < SEQ){
          float inv = 1.0f / lrun[m][j];
          float* hp = h + ((size_t)n*SEQ + row)*HID + hd*64;
          #pragma unroll
          for (int nd = 0; nd < 4; ++nd)
            hp[nd*16 + l16] += accO[m][nd][j] * inv;
        }
      }
    }
  }
}

// ---------------- head stage 1: logits ----------------
__global__ __launch_bounds__(256)
void head_logits(const float* __restrict__ h, const float* __restrict__ W,
                 const float* __restrict__ b, float* __restrict__ logits){
  int c0 = blockIdx.x * 8;
  __shared__ float Ws[512*8];
  int t = threadIdx.x;
  for (int i = t; i < 512*8; i += 256){
    int kx = i >> 3, c = i & 7;
    Ws[i] = W[(size_t)kx*OUTC + c0 + c];
  }
  __syncthreads();
  int n = t >> 2, g = t & 3;
  const float* hp = h + (size_t)n*SEQ*HID + g*128;
  float acc[8] = {};
  for (int kx = 0; kx < 128; ++kx){
    float hv = hp[kx];
    const float* wsr = &Ws[(g*128 + kx)*8];
    #pragma unroll
    for (int c = 0; c < 8; ++c) acc[c] += hv * wsr[c];
  }
  #pragma unroll
  for (int c = 0; c < 8; ++c){
    acc[c] += __shfl_xor(acc[c], 1);
    acc[c] += __shfl_xor(acc[c], 2);
  }
  if (g == 0){
    #pragma unroll
    for (int c = 0; c < 8; ++c)
      logits[(size_t)n*OUTC + c0 + c] = acc[c] + b[c0 + c];
  }
}

// ---------------- head stage 2: softmax ----------------
__global__ __launch_bounds__(256)
void head_softmax(const float* __restrict__ logits, float* __restrict__ out){
  int n = blockIdx.x, t = threadIdx.x;
  __shared__ float red[4];
  float v[4];
  #pragma unroll
  for (int j = 0; j < 4; ++j){
    int e = t + j*256;
    v[j] = (e < OUTC) ? logits[(size_t)n*OUTC + e] : -1e30f;
  }
  float mx = fmaxf(fmaxf(v[0], v[1]), fmaxf(v[2], v[3]));
  #pragma unroll
  for (int off = 32; off; off >>= 1) mx = fmaxf(mx, __shfl_xor(mx, off));
  if ((t & 63) == 0) red[t >> 6] = mx;
  __syncthreads();
  mx = fmaxf(fmaxf(red[0], red[1]), fmaxf(red[2], red[3]));
  __syncthreads();
  float sum = 0.f;
  #pragma unroll
  for (int j = 0; j < 4; ++j){ v[j] = __expf(v[j] - mx); sum += v[j]; }
  #pragma unroll
  for (int off = 32; off; off >>= 1) sum += __shfl_xor(sum, off);
  if ((t & 63) == 0) red[t >> 6] = sum;
  __syncthreads();
  sum = red[0] + red[1] + red[2] + red[3];
  float inv = 1.0f / sum;
  #pragma unroll
  for (int j = 0; j < 4; ++j){
    int e = t + j*256;
    if (e < OUTC) out[(size_t)n*OUTC + e] = v[j] * inv;
  }
}

extern "C" void kernel_launch(void* const* d_in, const int* in_sizes, int n_in,
                              void* d_out, int out_size, void* d_ws, size_t ws_size,
                              hipStream_t stream){
  const float* x       = (const float*)d_in[0];
  const float* embed_W = (const float*)d_in[1];
  const float* embed_b = (const float*)d_in[2];
  const float* cls     = (const float*)d_in[3];
  const float* ln1_g   = (const float*)d_in[4];
  const float* ln1_b   = (const float*)d_in[5];
  const float* qW      = (const float*)d_in[6];
  const float* qb      = (const float*)d_in[7];
  const float* kW      = (const float*)d_in[8];
  const float* kb      = (const float*)d_in[9];
  const float* vW      = (const float*)d_in[10];
  const float* vb      = (const float*)d_in[11];
  const float* ln2_g   = (const float*)d_in[12];
  const float* ln2_b   = (const float*)d_in[13];
  const float* mlp1_W  = (const float*)d_in[14];
  const float* mlp1_b  = (const float*)d_in[15];
  const float* mlp2_W  = (const float*)d_in[16];
  const float* mlp2_b  = (const float*)d_in[17];
  const float* head_W  = (const float*)d_in[18];
  const float* head_b  = (const float*)d_in[19];
  float* out = (float*)d_out;

  char* wsb = (char*)d_ws;
  float*  h   = (float*)wsb;                                   // M2*512 f32
  ushort* y   = (ushort*)(wsb + (size_t)M2*HID*4);             // M2*512 bf16
  float*  logits = (float*)y;                                  // reuse post-loop
  char*   un  = wsb + (size_t)M2*HID*4 + (size_t)M2*HID*2;     // union region
  ushort* qb_  = (ushort*)un;                                  // TT*512 bf16
  ushort* kb_  = qb_ + (size_t)TT*HID;
  ushort* vb_  = kb_ + (size_t)TT*HID;
  ushort* z1  = (ushort*)un;                                   // M2*2048 bf16
  ushort* p   = (ushort*)un;                                   // patches (pre-loop)
  char*   wts = un + (size_t)3*TT*HID*4;
  ushort* w1t = (ushort*)wts;
  ushort* w2t = w1t + (size_t)LAY*2048*512;
  ushort* wet = w2t + (size_t)LAY*2048*512;
  ushort* wqb = wet + (size_t)IN_DIM*HID;
  ushort* wkb = wqb + (size_t)LAY*NH*DH*DH;
  ushort* wvb = wkb + (size_t)LAY*NH*DH*DH;
  float*  pos = (float*)(wvb + (size_t)LAY*NH*DH*DH);          // SEQ*HID f32

  pos_kernel<<<SEQ, 512, 0, stream>>>(pos);
  convt_kernel<<<dim3(2048/32, 512/32, LAY), 256, 0, stream>>>(mlp1_W, w1t, 512, 2048);
  convt_kernel<<<dim3(512/32, 2048/32, LAY), 256, 0, stream>>>(mlp2_W, w2t, 2048, 512);
  convt_kernel<<<dim3(512/32, 768/32, 1),    256, 0, stream>>>(embed_W, wet, 768, 512);
  {
    int cnt = LAY*NH*DH*DH;
    int grd = (cnt + 255)/256;
    cvt_kernel<<<grd, 256, 0, stream>>>(qW, wqb, cnt);
    cvt_kernel<<<grd, 256, 0, stream>>>(kW, wkb, cnt);
    cvt_kernel<<<grd, 256, 0, stream>>>(vW, wvb, cnt);
  }

  patchify_kernel<<<(NPTOK*IN_DIM)/256, 256, 0, stream>>>(x, p);
  cls_kernel<<<BATCH, 512, 0, stream>>>(cls, pos, h);
  // embed: p[12800(pad)][768] @ wet^T -> h scatter (+pos), rows<NPTOK
  gemm_pipe<128, 3><<<(512/128)*(M2/128), 256, 0, stream>>>(
      p, wet, embed_b, h, IN_DIM, HID, NPTOK, 512/128, pos);

  for (int l = 0; l < LAY; ++l){
    ln_kernel<<<TT, 256, 0, stream>>>(h, ln1_g + l*HID, ln1_b + l*HID, y);
    qkv_mfma<<<dim3(M2/128, 24), 256, 0, stream>>>(
        y,
        wqb + (size_t)l*NH*DH*DH, wkb + (size_t)l*NH*DH*DH, wvb + (size_t)l*NH*DH*DH,
        qb + (size_t)l*HID, kb + (size_t)l*HID, vb + (size_t)l*HID,
        qb_, kb_, vb_);
    attn_kernel<<<BATCH*NH, 512, 0, stream>>>(qb_, kb_, vb_, h);
    ln_kernel<<<TT, 256, 0, stream>>>(h, ln2_g + l*HID, ln2_b + l*HID, y);
    // MLP1: 128x128 tiles, grid 1600, 5 blk/CU
    gemm_pipe<128, 1><<<(2048/128)*(M2/128), 256, 0, stream>>>(
        y, w1t + (size_t)l*2048*512, mlp1_b + (size_t)l*4*HID, z1,
        HID, 4*HID, TT, 2048/128, pos);
    // MLP2: 128x64 tiles, grid 800 -> ~3 blk/CU co-resident
    gemm_pipe<64, 2><<<(512/64)*(M2/128), 256, 0, stream>>>(
        z1, w2t + (size_t)l*2048*512, mlp2_b + (size_t)l*HID, h,
        4*HID, HID, TT, 512/64, pos);
  }

  head_logits<<<125, 256, 0, stream>>>(h, head_W, head_b, logits);
  head_softmax<<<BATCH, 256, 0, stream>>>(logits, out);
}

// Round 14
// 3612.067 us; speedup vs baseline: 1.6027x; 1.6027x over previous
//
#include <hip/hip_runtime.h>
#include <hip/hip_bf16.h>
#include <math.h>

#define LAY 20
#define HID 512
#define NH 8
#define DH 64
#define OUTC 1000
#define SEQ 197
#define SPAD 224
#define BATCH 64
#define TT (BATCH*SEQ)      /* 12608 tokens */
#define M2 12800            /* 100*128 */
#define NPTOK (BATCH*196)   /* 12544 */
#define IN_DIM 768

typedef __attribute__((ext_vector_type(8))) short bf16x8;
typedef __attribute__((ext_vector_type(4))) float f32x4;

__device__ __forceinline__ ushort f2bf(float f){
  __hip_bfloat16 h = __float2bfloat16(f);
  return *(ushort*)&h;
}
__device__ __forceinline__ float bf2f(ushort u){
  __hip_bfloat16 h = *(__hip_bfloat16*)&u;
  return __bfloat162float(h);
}

__device__ __forceinline__ float posemb(int i, int j){
  float je = (float)(j & ~1);
  float ang = (float)i * powf(10000.0f, -je * (1.0f/(float)HID));
  return (j & 1) ? cosf(ang) : sinf(ang);
}

__device__ __forceinline__ float gelu_exact(float x){
  return 0.5f * x * (1.0f + erff(x * 0.70710678118654752f));
}

__device__ __forceinline__ void gld_lds16(const ushort* g, ushort* l){
  __builtin_amdgcn_global_load_lds((const __attribute__((address_space(1))) void*)g,
                                   (__attribute__((address_space(3))) void*)l, 16, 0, 0);
}

// ------- pos embedding table [SEQ][HID] -------
__global__ __launch_bounds__(512)
void pos_kernel(float* __restrict__ pos){
  int i = blockIdx.x, j = threadIdx.x;
  pos[(size_t)i*HID + j] = posemb(i, j);
}

// ------- weight convert+transpose: src fp32 [R][C] -> dst bf16 [C][R] -------
__global__ __launch_bounds__(256)
void convt_kernel(const float* __restrict__ src, ushort* __restrict__ dst,
                  int R, int C){
  __shared__ float tile[32][33];
  const float* s = src + (size_t)blockIdx.z * R * C;
  ushort* d      = dst + (size_t)blockIdx.z * R * C;
  int r0 = blockIdx.y * 32, c0 = blockIdx.x * 32;
  int tc = threadIdx.x & 31, tr = threadIdx.x >> 5;
  #pragma unroll
  for (int i = 0; i < 4; ++i)
    tile[tr + i*8][tc] = s[(size_t)(r0 + tr + i*8)*C + c0 + tc];
  __syncthreads();
  #pragma unroll
  for (int i = 0; i < 4; ++i)
    d[(size_t)(c0 + tr + i*8)*R + r0 + tc] = f2bf(tile[tc][tr + i*8]);
}

// ------- elementwise fp32 -> bf16 convert -------
__global__ __launch_bounds__(256)
void cvt_kernel(const float* __restrict__ src, ushort* __restrict__ dst, int count){
  int idx = blockIdx.x * 256 + threadIdx.x;
  if (idx < count) dst[idx] = f2bf(src[idx]);
}

// ---------------- patchify ----------------
__global__ __launch_bounds__(256)
void patchify_kernel(const float* __restrict__ x, ushort* __restrict__ p){
  int idx = blockIdx.x * 256 + threadIdx.x;
  int r   = idx / 768, cdx = idx - r * 768;
  int n   = r / 196,  pp  = r - n * 196;
  int pr  = pp / 14,  pc  = pp - pr * 14;
  int c   = cdx >> 8, rem = cdx & 255;
  int ph  = rem >> 4, pw  = rem & 15;
  p[idx] = f2bf(x[ (((size_t)(n*3 + c)*224) + pr*16 + ph)*224 + pc*16 + pw ]);
}

// ---------------- cls row ----------------
__global__ __launch_bounds__(512)
void cls_kernel(const float* __restrict__ cls, const float* __restrict__ pos,
                float* __restrict__ h){
  int n = blockIdx.x, e = threadIdx.x;
  h[(size_t)n*SEQ*HID + e] = cls[e] + pos[e];
}

// ---------------- pipelined MFMA GEMM, 128xBN tile, BK=32, 4 blk/CU -------
// 256 threads (4 waves 2x2), double-buffered LDS (A 8KB + B BN*64 per buf).
// Slot-XOR swizzle slot^=((row>>1)&3) both sides. Counted vmcnt.
// NOTE: launch_bounds 2nd arg MUST be 4 — at 5 the 102-VGPR budget spills
// the 64-AGPR accumulator to scratch (round-13 regression: WRITE 51->328MB).
// EPI: 1 = bias+GELU -> bf16; 2 = bias + add into fp32 C rows<Mreal;
//      3 = embed: bias + pos add, scatter rows (rows<Mreal), fp32.
template<int BN, int EPI>
__global__ __launch_bounds__(256, 4)
void gemm_pipe(const ushort* __restrict__ A, const ushort* __restrict__ Bt,
               const float* __restrict__ bias, void* __restrict__ Cv,
               int K, int N, int Mreal, int NBX, const float* __restrict__ pos){
  constexpr int BM = 128;
  constexpr int MF = 4, NF = BN/32;  // per-wave 64 x (NF*16) region
  constexpr int BQ = BN/64;          // B staging issues per thread
  constexpr int TBS = 8192 + BN*64;  // bytes per buffer
  constexpr int ES = NF*16 + 12;     // epilogue staging stride (floats)
  __shared__ char lds[2*TBS];

  int t = threadIdx.x, lane = t & 63, wave = t >> 6;
  int wr = wave >> 1, wn = wave & 1;
  int l16 = lane & 15, g = lane >> 4;

  // bijective XCD-aware block swizzle
  int NB = gridDim.x;
  int q8 = NB >> 3, r8 = NB & 7;
  int xcd = blockIdx.x & 7, i8 = blockIdx.x >> 3;
  int swz = (xcd < r8 ? xcd*(q8+1) : r8*(q8+1) + (xcd-r8)*q8) + i8;
  int rb = (swz / NBX) * BM, cb = (swz % NBX) * BN;

  // staging: thread t -> row (t>>2) within a 64-row group; pre-swizzled
  // global 16B chunk (t&3)^((row>>1)&3); LDS dest linear.
  const int srow = t >> 2;
  const int kel  = ((t & 3) ^ ((srow >> 1) & 3)) * 8;
  const ushort* pA[2]; const ushort* pB[BQ];
  #pragma unroll
  for (int q = 0; q < 2; ++q)
    pA[q] = A + (size_t)(rb + q*64 + srow)*K + kel;
  #pragma unroll
  for (int q = 0; q < BQ; ++q)
    pB[q] = Bt + (size_t)(cb + q*64 + srow)*K + kel;
  const int sdst = t*16;

  // ds_read offsets with matching slot-XOR ((row>>1)&3 == (l16>>1)&3)
  const int sx = (l16 >> 1) & 3;
  int aoff[MF], boff[NF];
  #pragma unroll
  for (int mf = 0; mf < MF; ++mf)
    aoff[mf] = (wr*64 + mf*16 + l16)*64 + ((g ^ sx) << 4);
  #pragma unroll
  for (int nf = 0; nf < NF; ++nf)
    boff[nf] = 8192 + (wn*(NF*16) + nf*16 + l16)*64 + ((g ^ sx) << 4);

  f32x4 acc[MF][NF];
  #pragma unroll
  for (int mf = 0; mf < MF; ++mf)
    #pragma unroll
    for (int nf = 0; nf < NF; ++nf)
      acc[mf][nf] = (f32x4){0.f,0.f,0.f,0.f};

  // prologue: stage tile 0 into buffer 0
  #pragma unroll
  for (int q = 0; q < 2; ++q)
    gld_lds16(pA[q], (ushort*)(lds + q*4096 + sdst));
  #pragma unroll
  for (int q = 0; q < BQ; ++q)
    gld_lds16(pB[q], (ushort*)(lds + 8192 + q*4096 + sdst));

  int NT = K / 32;
  for (int tt = 0; tt < NT; ++tt){
    const char* cur = lds + (tt & 1)*TBS;
    char* nxt = lds + ((tt & 1) ^ 1)*TBS;
    bool pf = (tt + 1 < NT);
    if (pf){
      const size_t kb = (size_t)(tt + 1) * 32;
      #pragma unroll
      for (int q = 0; q < 2; ++q)
        gld_lds16(pA[q] + kb, (ushort*)(nxt + q*4096 + sdst));
      #pragma unroll
      for (int q = 0; q < BQ; ++q)
        gld_lds16(pB[q] + kb, (ushort*)(nxt + 8192 + q*4096 + sdst));
      if constexpr (BQ == 2)
        asm volatile("s_waitcnt vmcnt(4)" ::: "memory");
      else
        asm volatile("s_waitcnt vmcnt(3)" ::: "memory");
    } else {
      asm volatile("s_waitcnt vmcnt(0)" ::: "memory");
    }
    __builtin_amdgcn_s_barrier();   // tile tt data visible

    bf16x8 af[MF], bfr[NF];
    #pragma unroll
    for (int nf = 0; nf < NF; ++nf)
      bfr[nf] = *(const bf16x8*)(cur + boff[nf]);
    #pragma unroll
    for (int mf = 0; mf < MF; ++mf)
      af[mf] = *(const bf16x8*)(cur + aoff[mf]);

    __builtin_amdgcn_s_setprio(1);
    #pragma unroll
    for (int mf = 0; mf < MF; ++mf)
      #pragma unroll
      for (int nf = 0; nf < NF; ++nf)
        acc[mf][nf] = __builtin_amdgcn_mfma_f32_16x16x32_bf16(af[mf], bfr[nf], acc[mf][nf], 0, 0, 0);
    __builtin_amdgcn_s_setprio(0);
    __builtin_amdgcn_s_barrier();   // all waves done reading cur
  }

  // -------- coalesced epilogue via per-wave LDS transpose (static idx) --
  float bvv[NF];
  #pragma unroll
  for (int nf = 0; nf < NF; ++nf)
    bvv[nf] = bias[cb + wn*(NF*16) + nf*16 + l16];
  float* eps = (float*)(lds + wave*(16*ES*4));

  #pragma unroll
  for (int mf = 0; mf < MF; ++mf){
    #pragma unroll
    for (int nf = 0; nf < NF; ++nf)
      #pragma unroll
      for (int j = 0; j < 4; ++j){
        float val = acc[mf][nf][j] + bvv[nf];
        if (EPI == 1) val = gelu_exact(val);
        eps[(g*4+j)*ES + nf*16 + l16] = val;
      }
    #pragma unroll
    for (int i = 0; i < NF; ++i){
      int id = i*64 + lane;
      int r = id / (4*NF), c4 = id % (4*NF);
      float4 vv = *(float4*)&eps[r*ES + c4*4];
      int grow = rb + wr*64 + mf*16 + r;
      int gcol = cb + wn*(NF*16) + c4*4;
      if (EPI == 1){
        ushort4 u;
        u.x = f2bf(vv.x); u.y = f2bf(vv.y); u.z = f2bf(vv.z); u.w = f2bf(vv.w);
        *(ushort4*)&((ushort*)Cv)[(size_t)grow*N + gcol] = u;
      } else if (EPI == 2){
        if (grow < Mreal){
          float* cp = &((float*)Cv)[(size_t)grow*N + gcol];
          float4 o = *(float4*)cp;
          o.x += vv.x; o.y += vv.y; o.z += vv.z; o.w += vv.w;
          *(float4*)cp = o;
        }
      } else { // EPI == 3
        if (grow < Mreal){
          int bn = grow / 196, sp = grow - bn*196;
          float4 pv = *(const float4*)&pos[(size_t)(1+sp)*HID + gcol];
          vv.x += pv.x; vv.y += pv.y; vv.z += pv.z; vv.w += pv.w;
          *(float4*)&((float*)Cv)[((size_t)bn*SEQ + 1 + sp)*HID + gcol] = vv;
        }
      }
    }
  }
}

// ---------------- LayerNorm (fp32 in, bf16 out) ----------------
__global__ __launch_bounds__(256)
void ln_kernel(const float* __restrict__ x, const float* __restrict__ g,
               const float* __restrict__ b, ushort* __restrict__ y){
  int tok = blockIdx.x, t = threadIdx.x;
  const float* xp = x + (size_t)tok*HID;
  float v1 = xp[t], v2 = xp[t + 256];
  __shared__ float red[4];
  float s = v1 + v2;
  #pragma unroll
  for (int off = 32; off; off >>= 1) s += __shfl_xor(s, off);
  if ((t & 63) == 0) red[t >> 6] = s;
  __syncthreads();
  float mean = (red[0] + red[1] + red[2] + red[3]) * (1.0f/512.0f);
  __syncthreads();
  float d1 = v1 - mean, d2 = v2 - mean;
  s = d1*d1 + d2*d2;
  #pragma unroll
  for (int off = 32; off; off >>= 1) s += __shfl_xor(s, off);
  if ((t & 63) == 0) red[t >> 6] = s;
  __syncthreads();
  float var = (red[0] + red[1] + red[2] + red[3]) * (1.0f/512.0f);
  float rs  = rsqrtf(var + 1e-5f);
  ushort* yp = y + (size_t)tok*HID;
  yp[t]       = f2bf(d1*rs*g[t]       + b[t]);
  yp[t + 256] = f2bf(d2*rs*g[t + 256] + b[t + 256]);
}

// ---------------- MFMA QKV projection, coalesced row-major outputs -------
__global__ __launch_bounds__(256)
void qkv_mfma(const ushort* __restrict__ y,
              const ushort* __restrict__ wqb, const ushort* __restrict__ wkb,
              const ushort* __restrict__ wvb,
              const float* __restrict__ bq, const float* __restrict__ bk,
              const float* __restrict__ bv,
              ushort* __restrict__ q, ushort* __restrict__ k,
              ushort* __restrict__ v){
  __shared__ short As[128*64];
  __shared__ short Bs[64*64];
  int t = threadIdx.x;
  int lane = t & 63, wave = t >> 6;
  int l16 = lane & 15, g = lane >> 4;
  int p  = blockIdx.y >> 3, hh = blockIdx.y & 7;
  int rb = blockIdx.x * 128;

  const ushort* W; const float* bias; ushort* out;
  if (p == 0)      { W = wqb; bias = bq; out = q; }
  else if (p == 1) { W = wkb; bias = bk; out = k; }
  else             { W = wvb; bias = bv; out = v; }
  W    += (size_t)hh * 64 * 64;
  bias += hh * 64;

  int srow = t >> 3, skoff = (t & 7) * 8;
  const ushort* Ab = y + (size_t)(rb + srow)*HID + hh*64 + skoff;
  const ushort* Bb = W + (size_t)srow*64 + skoff;
  #pragma unroll
  for (int i = 0; i < 4; ++i)
    gld_lds16(Ab + (size_t)(i*32)*HID, (ushort*)&As[t*8 + i*2048]);
  #pragma unroll
  for (int i = 0; i < 2; ++i)
    gld_lds16(Bb + (size_t)(i*32)*64, (ushort*)&Bs[t*8 + i*2048]);
  __syncthreads();

  f32x4 acc[2][4];
  #pragma unroll
  for (int m = 0; m < 2; ++m)
    #pragma unroll
    for (int n = 0; n < 4; ++n)
      acc[m][n] = (f32x4){0.f,0.f,0.f,0.f};

  #pragma unroll
  for (int kc = 0; kc < 2; ++kc){
    bf16x8 af[2], bfr[4];
    #pragma unroll
    for (int m = 0; m < 2; ++m)
      af[m] = *(bf16x8*)&As[(wave*32 + m*16 + l16)*64 + kc*32 + g*8];
    #pragma unroll
    for (int n = 0; n < 4; ++n)
      bfr[n] = *(bf16x8*)&Bs[(n*16 + l16)*64 + kc*32 + g*8];
    #pragma unroll
    for (int m = 0; m < 2; ++m)
      #pragma unroll
      for (int n = 0; n < 4; ++n)
        acc[m][n] = __builtin_amdgcn_mfma_f32_16x16x32_bf16(af[m], bfr[n], acc[m][n], 0, 0, 0);
  }
  __syncthreads();   // reuse As for epilogue staging

  float bvv[4];
  #pragma unroll
  for (int nd = 0; nd < 4; ++nd) bvv[nd] = bias[nd*16 + l16];
  ushort* eps = (ushort*)As + wave*(16*72);
  #pragma unroll
  for (int mch = 0; mch < 2; ++mch){
    #pragma unroll
    for (int nd = 0; nd < 4; ++nd)
      #pragma unroll
      for (int j = 0; j < 4; ++j)
        eps[(g*4+j)*72 + nd*16 + l16] = f2bf(acc[mch][nd][j] + bvv[nd]);
    #pragma unroll
    for (int i = 0; i < 2; ++i){
      int id = i*64 + lane;
      int r = id >> 3, c8 = id & 7;
      uint4 vv = *(uint4*)&eps[r*72 + c8*8];
      int tok = rb + wave*32 + mch*16 + r;
      if (tok < TT)
        *(uint4*)&out[(size_t)tok*HID + hh*64 + c8*8] = vv;
    }
  }
}

// ---------------- MFMA flash attention + residual add into h ----------------
__global__ __launch_bounds__(512, 4)
void attn_kernel(const ushort* __restrict__ q, const ushort* __restrict__ k,
                 const ushort* __restrict__ v, float* __restrict__ h){
  __shared__ ushort Ks[SPAD*64];
  __shared__ ushort Vs[64*256];
  __shared__ ushort Ps[8][32*40];
  int nh = blockIdx.x;
  int n = nh >> 3, hd = nh & 7;
  int t = threadIdx.x;
  int lane = t & 63, wave = t >> 6;
  int l16 = lane & 15, g = lane >> 4;

  const ushort* kbase = k + ((size_t)n*SEQ)*HID + hd*64;
  for (int c = t; c < 224*8; c += 512){
    int s = c >> 3, c8 = (c & 7) * 8;
    int sr = s < SEQ ? s : SEQ-1;
    uint4 val = *(const uint4*)&kbase[(size_t)sr*HID + c8];
    int byte = s*128 + c8*2;
    byte ^= (s & 7) << 4;
    *(uint4*)((char*)Ks + byte) = val;
  }
  const ushort* vbase = v + ((size_t)n*SEQ)*HID + hd*64;
  for (int c = t; c < 224*8; c += 512){
    int s = c >> 3, d8 = (c & 7) * 8;
    uint4 val = {0u,0u,0u,0u};
    if (s < SEQ) val = *(const uint4*)&vbase[(size_t)s*HID + d8];
    ushort* vsp = (ushort*)Vs;
    #pragma unroll
    for (int e = 0; e < 8; ++e){
      int d = d8 + e;
      int swzi = ((d & 7) ^ ((d >> 3) & 7)) << 4;
      int byte = d*512 + ((s*2) ^ swzi);
      vsp[byte >> 1] = ((ushort*)&val)[e];
    }
  }

  int qrow0 = wave * 32;
  bool wactive = qrow0 < SEQ;
  bf16x8 aq[2][2];
  if (wactive){
    #pragma unroll
    for (int m = 0; m < 2; ++m){
      int row = qrow0 + m*16 + l16;
      int sr = row < SEQ ? row : SEQ-1;
      const ushort* qp = q + ((size_t)n*SEQ + sr)*HID + hd*64;
      #pragma unroll
      for (int kc = 0; kc < 2; ++kc)
        aq[m][kc] = *(const bf16x8*)&qp[kc*32 + g*8];
    }
  }
  __syncthreads();

  if (wactive){
    ushort* myP = &Ps[wave][0];
    f32x4 accO[2][4];
    float mrun[2][4], lrun[2][4];
    #pragma unroll
    for (int m = 0; m < 2; ++m){
      #pragma unroll
      for (int nd = 0; nd < 4; ++nd) accO[m][nd] = (f32x4){0.f,0.f,0.f,0.f};
      #pragma unroll
      for (int j = 0; j < 4; ++j){ mrun[m][j] = -1e30f; lrun[m][j] = 0.f; }
    }

    for (int kt = 0; kt < 7; ++kt){
      f32x4 accS[2][2];
      #pragma unroll
      for (int m = 0; m < 2; ++m)
        #pragma unroll
        for (int nn = 0; nn < 2; ++nn) accS[m][nn] = (f32x4){0.f,0.f,0.f,0.f};
      #pragma unroll
      for (int kc = 0; kc < 2; ++kc){
        bf16x8 bk[2];
        #pragma unroll
        for (int nn = 0; nn < 2; ++nn){
          int srow = kt*32 + nn*16 + l16;
          int byte = srow*128 + kc*64 + g*16;
          byte ^= (srow & 7) << 4;
          bk[nn] = *(const bf16x8*)((const char*)Ks + byte);
        }
        #pragma unroll
        for (int m = 0; m < 2; ++m)
          #pragma unroll
          for (int nn = 0; nn < 2; ++nn)
            accS[m][nn] = __builtin_amdgcn_mfma_f32_16x16x32_bf16(aq[m][kc], bk[nn], accS[m][nn], 0, 0, 0);
      }
      bool kv0 = (kt*32 + l16) < SEQ;
      bool kv1 = (kt*32 + 16 + l16) < SEQ;
      #pragma unroll
      for (int m = 0; m < 2; ++m){
        #pragma unroll
        for (int j = 0; j < 4; ++j){
          float s0 = kv0 ? accS[m][0][j]*0.125f : -1e30f;
          float s1 = kv1 ? accS[m][1][j]*0.125f : -1e30f;
          float mx = fmaxf(s0, s1);
          mx = fmaxf(mx, __shfl_xor(mx, 1));
          mx = fmaxf(mx, __shfl_xor(mx, 2));
          mx = fmaxf(mx, __shfl_xor(mx, 4));
          mx = fmaxf(mx, __shfl_xor(mx, 8));
          float mold = mrun[m][j];
          float mnew = fmaxf(mold, mx);
          float corr = __expf(mold - mnew);
          mrun[m][j] = mnew;
          float p0 = __expf(s0 - mnew);
          float p1 = __expf(s1 - mnew);
          float rs = p0 + p1;
          rs += __shfl_xor(rs, 1);
          rs += __shfl_xor(rs, 2);
          rs += __shfl_xor(rs, 4);
          rs += __shfl_xor(rs, 8);
          lrun[m][j] = lrun[m][j]*corr + rs;
          #pragma unroll
          for (int nd = 0; nd < 4; ++nd) accO[m][nd][j] *= corr;
          int prow = m*16 + g*4 + j;
          myP[prow*40 + l16]      = f2bf(p0);
          myP[prow*40 + 16 + l16] = f2bf(p1);
        }
      }
      bf16x8 ap[2], bv[4];
      #pragma unroll
      for (int m = 0; m < 2; ++m)
        ap[m] = *(const bf16x8*)&myP[(m*16 + l16)*40 + g*8];
      #pragma unroll
      for (int nd = 0; nd < 4; ++nd){
        int d = nd*16 + l16;
        int byte = d*512 + kt*64 + g*16;
        byte ^= ((d & 7) ^ ((d >> 3) & 7)) << 4;
        bv[nd] = *(const bf16x8*)((const char*)Vs + byte);
      }
      #pragma unroll
      for (int m = 0; m < 2; ++m)
        #pragma unroll
        for (int nd = 0; nd < 4; ++nd)
          accO[m][nd] = __builtin_amdgcn_mfma_f32_16x16x32_bf16(ap[m], bv[nd], accO[m][nd], 0, 0, 0);
    }

    #pragma unroll
    for (int m = 0; m < 2; ++m){
      #pragma unroll
      for (int j = 0; j < 4; ++j){
        int row = qrow0 + m*16 + g*4 + j;
        if (row < SEQ){
          float inv = 1.0f / lrun[m][j];
          float* hp = h + ((size_t)n*SEQ + row)*HID + hd*64;
          #pragma unroll
          for (int nd = 0; nd < 4; ++nd)
            hp[nd*16 + l16] += accO[m][nd][j] * inv;
        }
      }
    }
  }
}

// ---------------- head stage 1: logits ----------------
__global__ __launch_bounds__(256)
void head_logits(const float* __restrict__ h, const float* __restrict__ W,
                 const float* __restrict__ b, float* __restrict__ logits){
  int c0 = blockIdx.x * 8;
  __shared__ float Ws[512*8];
  int t = threadIdx.x;
  for (int i = t; i < 512*8; i += 256){
    int kx = i >> 3, c = i & 7;
    Ws[i] = W[(size_t)kx*OUTC + c0 + c];
  }
  __syncthreads();
  int n = t >> 2, g = t & 3;
  const float* hp = h + (size_t)n*SEQ*HID + g*128;
  float acc[8] = {};
  for (int kx = 0; kx < 128; ++kx){
    float hv = hp[kx];
    const float* wsr = &Ws[(g*128 + kx)*8];
    #pragma unroll
    for (int c = 0; c < 8; ++c) acc[c] += hv * wsr[c];
  }
  #pragma unroll
  for (int c = 0; c < 8; ++c){
    acc[c] += __shfl_xor(acc[c], 1);
    acc[c] += __shfl_xor(acc[c], 2);
  }
  if (g == 0){
    #pragma unroll
    for (int c = 0; c < 8; ++c)
      logits[(size_t)n*OUTC + c0 + c] = acc[c] + b[c0 + c];
  }
}

// ---------------- head stage 2: softmax ----------------
__global__ __launch_bounds__(256)
void head_softmax(const float* __restrict__ logits, float* __restrict__ out){
  int n = blockIdx.x, t = threadIdx.x;
  __shared__ float red[4];
  float v[4];
  #pragma unroll
  for (int j = 0; j < 4; ++j){
    int e = t + j*256;
    v[j] = (e < OUTC) ? logits[(size_t)n*OUTC + e] : -1e30f;
  }
  float mx = fmaxf(fmaxf(v[0], v[1]), fmaxf(v[2], v[3]));
  #pragma unroll
  for (int off = 32; off; off >>= 1) mx = fmaxf(mx, __shfl_xor(mx, off));
  if ((t & 63) == 0) red[t >> 6] = mx;
  __syncthreads();
  mx = fmaxf(fmaxf(red[0], red[1]), fmaxf(red[2], red[3]));
  __syncthreads();
  float sum = 0.f;
  #pragma unroll
  for (int j = 0; j < 4; ++j){ v[j] = __expf(v[j] - mx); sum += v[j]; }
  #pragma unroll
  for (int off = 32; off; off >>= 1) sum += __shfl_xor(sum, off);
  if ((t & 63) == 0) red[t >> 6] = sum;
  __syncthreads();
  sum = red[0] + red[1] + red[2] + red[3];
  float inv = 1.0f / sum;
  #pragma unroll
  for (int j = 0; j < 4; ++j){
    int e = t + j*256;
    if (e < OUTC) out[(size_t)n*OUTC + e] = v[j] * inv;
  }
}

extern "C" void kernel_launch(void* const* d_in, const int* in_sizes, int n_in,
                              void* d_out, int out_size, void* d_ws, size_t ws_size,
                              hipStream_t stream){
  const float* x       = (const float*)d_in[0];
  const float* embed_W = (const float*)d_in[1];
  const float* embed_b = (const float*)d_in[2];
  const float* cls     = (const float*)d_in[3];
  const float* ln1_g   = (const float*)d_in[4];
  const float* ln1_b   = (const float*)d_in[5];
  const float* qW      = (const float*)d_in[6];
  const float* qb      = (const float*)d_in[7];
  const float* kW      = (const float*)d_in[8];
  const float* kb      = (const float*)d_in[9];
  const float* vW      = (const float*)d_in[10];
  const float* vb      = (const float*)d_in[11];
  const float* ln2_g   = (const float*)d_in[12];
  const float* ln2_b   = (const float*)d_in[13];
  const float* mlp1_W  = (const float*)d_in[14];
  const float* mlp1_b  = (const float*)d_in[15];
  const float* mlp2_W  = (const float*)d_in[16];
  const float* mlp2_b  = (const float*)d_in[17];
  const float* head_W  = (const float*)d_in[18];
  const float* head_b  = (const float*)d_in[19];
  float* out = (float*)d_out;

  char* wsb = (char*)d_ws;
  float*  h   = (float*)wsb;                                   // M2*512 f32
  ushort* y   = (ushort*)(wsb + (size_t)M2*HID*4);             // M2*512 bf16
  float*  logits = (float*)y;                                  // reuse post-loop
  char*   un  = wsb + (size_t)M2*HID*4 + (size_t)M2*HID*2;     // union region
  ushort* qb_  = (ushort*)un;                                  // TT*512 bf16
  ushort* kb_  = qb_ + (size_t)TT*HID;
  ushort* vb_  = kb_ + (size_t)TT*HID;
  ushort* z1  = (ushort*)un;                                   // M2*2048 bf16
  ushort* p   = (ushort*)un;                                   // patches (pre-loop)
  char*   wts = un + (size_t)3*TT*HID*4;
  ushort* w1t = (ushort*)wts;
  ushort* w2t = w1t + (size_t)LAY*2048*512;
  ushort* wet = w2t + (size_t)LAY*2048*512;
  ushort* wqb = wet + (size_t)IN_DIM*HID;
  ushort* wkb = wqb + (size_t)LAY*NH*DH*DH;
  ushort* wvb = wkb + (size_t)LAY*NH*DH*DH;
  float*  pos = (float*)(wvb + (size_t)LAY*NH*DH*DH);          // SEQ*HID f32

  pos_kernel<<<SEQ, 512, 0, stream>>>(pos);
  convt_kernel<<<dim3(2048/32, 512/32, LAY), 256, 0, stream>>>(mlp1_W, w1t, 512, 2048);
  convt_kernel<<<dim3(512/32, 2048/32, LAY), 256, 0, stream>>>(mlp2_W, w2t, 2048, 512);
  convt_kernel<<<dim3(512/32, 768/32, 1),    256, 0, stream>>>(embed_W, wet, 768, 512);
  {
    int cnt = LAY*NH*DH*DH;
    int grd = (cnt + 255)/256;
    cvt_kernel<<<grd, 256, 0, stream>>>(qW, wqb, cnt);
    cvt_kernel<<<grd, 256, 0, stream>>>(kW, wkb, cnt);
    cvt_kernel<<<grd, 256, 0, stream>>>(vW, wvb, cnt);
  }

  patchify_kernel<<<(NPTOK*IN_DIM)/256, 256, 0, stream>>>(x, p);
  cls_kernel<<<BATCH, 512, 0, stream>>>(cls, pos, h);
  // embed: p[12800(pad)][768] @ wet^T -> h scatter (+pos), rows<NPTOK
  gemm_pipe<128, 3><<<(512/128)*(M2/128), 256, 0, stream>>>(
      p, wet, embed_b, h, IN_DIM, HID, NPTOK, 512/128, pos);

  for (int l = 0; l < LAY; ++l){
    ln_kernel<<<TT, 256, 0, stream>>>(h, ln1_g + l*HID, ln1_b + l*HID, y);
    qkv_mfma<<<dim3(M2/128, 24), 256, 0, stream>>>(
        y,
        wqb + (size_t)l*NH*DH*DH, wkb + (size_t)l*NH*DH*DH, wvb + (size_t)l*NH*DH*DH,
        qb + (size_t)l*HID, kb + (size_t)l*HID, vb + (size_t)l*HID,
        qb_, kb_, vb_);
    attn_kernel<<<BATCH*NH, 512, 0, stream>>>(qb_, kb_, vb_, h);
    ln_kernel<<<TT, 256, 0, stream>>>(h, ln2_g + l*HID, ln2_b + l*HID, y);
    // MLP1: 128x128 tiles, grid 1600, 4 blk/CU
    gemm_pipe<128, 1><<<(2048/128)*(M2/128), 256, 0, stream>>>(
        y, w1t + (size_t)l*2048*512, mlp1_b + (size_t)l*4*HID, z1,
        HID, 4*HID, TT, 2048/128, pos);
    // MLP2: 128x64 tiles, grid 800 -> all co-resident at 4 blk/CU
    gemm_pipe<64, 2><<<(512/64)*(M2/128), 256, 0, stream>>>(
        z1, w2t + (size_t)l*2048*512, mlp2_b + (size_t)l*HID, h,
        4*HID, HID, TT, 512/64, pos);
  }

  head_logits<<<125, 256, 0, stream>>>(h, head_W, head_b, logits);
  head_softmax<<<BATCH, 256, 0, stream>>>(logits, out);
}

// Round 15
// 3170.068 us; speedup vs baseline: 1.8261x; 1.1394x over previous
//
#include <hip/hip_runtime.h>
#include <hip/hip_bf16.h>
#include <math.h>

#define LAY 20
#define HID 512
#define NH 8
#define DH 64
#define OUTC 1000
#define SEQ 197
#define SPAD 224
#define BATCH 64
#define TT (BATCH*SEQ)      /* 12608 tokens */
#define M2 12800            /* 100*128 */
#define NPTOK (BATCH*196)   /* 12544 */
#define IN_DIM 768

typedef __attribute__((ext_vector_type(8))) short bf16x8;
typedef __attribute__((ext_vector_type(4))) float f32x4;

__device__ __forceinline__ ushort f2bf(float f){
  __hip_bfloat16 h = __float2bfloat16(f);
  return *(ushort*)&h;
}
__device__ __forceinline__ float bf2f(ushort u){
  __hip_bfloat16 h = *(__hip_bfloat16*)&u;
  return __bfloat162float(h);
}

__device__ __forceinline__ float posemb(int i, int j){
  float je = (float)(j & ~1);
  float ang = (float)i * powf(10000.0f, -je * (1.0f/(float)HID));
  return (j & 1) ? cosf(ang) : sinf(ang);
}

__device__ __forceinline__ float gelu_exact(float x){
  return 0.5f * x * (1.0f + erff(x * 0.70710678118654752f));
}

__device__ __forceinline__ void gld_lds16(const ushort* g, ushort* l){
  __builtin_amdgcn_global_load_lds((const __attribute__((address_space(1))) void*)g,
                                   (__attribute__((address_space(3))) void*)l, 16, 0, 0);
}

// ------- pos embedding table [SEQ][HID] -------
__global__ __launch_bounds__(512)
void pos_kernel(float* __restrict__ pos){
  int i = blockIdx.x, j = threadIdx.x;
  pos[(size_t)i*HID + j] = posemb(i, j);
}

// ------- weight convert+transpose: src fp32 [R][C] -> dst bf16 [C][R] -------
__global__ __launch_bounds__(256)
void convt_kernel(const float* __restrict__ src, ushort* __restrict__ dst,
                  int R, int C){
  __shared__ float tile[32][33];
  const float* s = src + (size_t)blockIdx.z * R * C;
  ushort* d      = dst + (size_t)blockIdx.z * R * C;
  int r0 = blockIdx.y * 32, c0 = blockIdx.x * 32;
  int tc = threadIdx.x & 31, tr = threadIdx.x >> 5;
  #pragma unroll
  for (int i = 0; i < 4; ++i)
    tile[tr + i*8][tc] = s[(size_t)(r0 + tr + i*8)*C + c0 + tc];
  __syncthreads();
  #pragma unroll
  for (int i = 0; i < 4; ++i)
    d[(size_t)(c0 + tr + i*8)*R + r0 + tc] = f2bf(tile[tc][tr + i*8]);
}

// ------- elementwise fp32 -> bf16 convert -------
__global__ __launch_bounds__(256)
void cvt_kernel(const float* __restrict__ src, ushort* __restrict__ dst, int count){
  int idx = blockIdx.x * 256 + threadIdx.x;
  if (idx < count) dst[idx] = f2bf(src[idx]);
}

// ---------------- patchify ----------------
__global__ __launch_bounds__(256)
void patchify_kernel(const float* __restrict__ x, ushort* __restrict__ p){
  int idx = blockIdx.x * 256 + threadIdx.x;
  int r   = idx / 768, cdx = idx - r * 768;
  int n   = r / 196,  pp  = r - n * 196;
  int pr  = pp / 14,  pc  = pp - pr * 14;
  int c   = cdx >> 8, rem = cdx & 255;
  int ph  = rem >> 4, pw  = rem & 15;
  p[idx] = f2bf(x[ (((size_t)(n*3 + c)*224) + pr*16 + ph)*224 + pc*16 + pw ]);
}

// ---------------- cls row ----------------
__global__ __launch_bounds__(512)
void cls_kernel(const float* __restrict__ cls, const float* __restrict__ pos,
                float* __restrict__ h){
  int n = blockIdx.x, e = threadIdx.x;
  h[(size_t)n*SEQ*HID + e] = cls[e] + pos[e];
}

// ---------------- pipelined MFMA GEMM, 128x128 tile, BK=32, 4 blk/CU -------
// NOTE: launch_bounds 2nd arg MUST be 4 — at 5 the 102-VGPR budget spills
// the 64-AGPR accumulator to scratch (round-13 regression).
// NOTE: BN=64 regressed MLP2 (round-14: 47->62us) — barrier cost per K-tile
// is fixed, halving MFMA/phase hurts. Keep BN=128.
template<int BN, int EPI>
__global__ __launch_bounds__(256, 4)
void gemm_pipe(const ushort* __restrict__ A, const ushort* __restrict__ Bt,
               const float* __restrict__ bias, void* __restrict__ Cv,
               int K, int N, int Mreal, int NBX, const float* __restrict__ pos){
  constexpr int BM = 128;
  constexpr int MF = 4, NF = BN/32;
  constexpr int BQ = BN/64;
  constexpr int TBS = 8192 + BN*64;
  constexpr int ES = NF*16 + 12;
  __shared__ char lds[2*TBS];

  int t = threadIdx.x, lane = t & 63, wave = t >> 6;
  int wr = wave >> 1, wn = wave & 1;
  int l16 = lane & 15, g = lane >> 4;

  int NB = gridDim.x;
  int q8 = NB >> 3, r8 = NB & 7;
  int xcd = blockIdx.x & 7, i8 = blockIdx.x >> 3;
  int swz = (xcd < r8 ? xcd*(q8+1) : r8*(q8+1) + (xcd-r8)*q8) + i8;
  int rb = (swz / NBX) * BM, cb = (swz % NBX) * BN;

  const int srow = t >> 2;
  const int kel  = ((t & 3) ^ ((srow >> 1) & 3)) * 8;
  const ushort* pA[2]; const ushort* pB[BQ];
  #pragma unroll
  for (int q = 0; q < 2; ++q)
    pA[q] = A + (size_t)(rb + q*64 + srow)*K + kel;
  #pragma unroll
  for (int q = 0; q < BQ; ++q)
    pB[q] = Bt + (size_t)(cb + q*64 + srow)*K + kel;
  const int sdst = t*16;

  const int sx = (l16 >> 1) & 3;
  int aoff[MF], boff[NF];
  #pragma unroll
  for (int mf = 0; mf < MF; ++mf)
    aoff[mf] = (wr*64 + mf*16 + l16)*64 + ((g ^ sx) << 4);
  #pragma unroll
  for (int nf = 0; nf < NF; ++nf)
    boff[nf] = 8192 + (wn*(NF*16) + nf*16 + l16)*64 + ((g ^ sx) << 4);

  f32x4 acc[MF][NF];
  #pragma unroll
  for (int mf = 0; mf < MF; ++mf)
    #pragma unroll
    for (int nf = 0; nf < NF; ++nf)
      acc[mf][nf] = (f32x4){0.f,0.f,0.f,0.f};

  #pragma unroll
  for (int q = 0; q < 2; ++q)
    gld_lds16(pA[q], (ushort*)(lds + q*4096 + sdst));
  #pragma unroll
  for (int q = 0; q < BQ; ++q)
    gld_lds16(pB[q], (ushort*)(lds + 8192 + q*4096 + sdst));

  int NT = K / 32;
  for (int tt = 0; tt < NT; ++tt){
    const char* cur = lds + (tt & 1)*TBS;
    char* nxt = lds + ((tt & 1) ^ 1)*TBS;
    bool pf = (tt + 1 < NT);
    if (pf){
      const size_t kb = (size_t)(tt + 1) * 32;
      #pragma unroll
      for (int q = 0; q < 2; ++q)
        gld_lds16(pA[q] + kb, (ushort*)(nxt + q*4096 + sdst));
      #pragma unroll
      for (int q = 0; q < BQ; ++q)
        gld_lds16(pB[q] + kb, (ushort*)(nxt + 8192 + q*4096 + sdst));
      if constexpr (BQ == 2)
        asm volatile("s_waitcnt vmcnt(4)" ::: "memory");
      else
        asm volatile("s_waitcnt vmcnt(3)" ::: "memory");
    } else {
      asm volatile("s_waitcnt vmcnt(0)" ::: "memory");
    }
    __builtin_amdgcn_s_barrier();

    bf16x8 af[MF], bfr[NF];
    #pragma unroll
    for (int nf = 0; nf < NF; ++nf)
      bfr[nf] = *(const bf16x8*)(cur + boff[nf]);
    #pragma unroll
    for (int mf = 0; mf < MF; ++mf)
      af[mf] = *(const bf16x8*)(cur + aoff[mf]);

    __builtin_amdgcn_s_setprio(1);
    #pragma unroll
    for (int mf = 0; mf < MF; ++mf)
      #pragma unroll
      for (int nf = 0; nf < NF; ++nf)
        acc[mf][nf] = __builtin_amdgcn_mfma_f32_16x16x32_bf16(af[mf], bfr[nf], acc[mf][nf], 0, 0, 0);
    __builtin_amdgcn_s_setprio(0);
    __builtin_amdgcn_s_barrier();
  }

  float bvv[NF];
  #pragma unroll
  for (int nf = 0; nf < NF; ++nf)
    bvv[nf] = bias[cb + wn*(NF*16) + nf*16 + l16];
  float* eps = (float*)(lds + wave*(16*ES*4));

  #pragma unroll
  for (int mf = 0; mf < MF; ++mf){
    #pragma unroll
    for (int nf = 0; nf < NF; ++nf)
      #pragma unroll
      for (int j = 0; j < 4; ++j){
        float val = acc[mf][nf][j] + bvv[nf];
        if (EPI == 1) val = gelu_exact(val);
        eps[(g*4+j)*ES + nf*16 + l16] = val;
      }
    #pragma unroll
    for (int i = 0; i < NF; ++i){
      int id = i*64 + lane;
      int r = id / (4*NF), c4 = id % (4*NF);
      float4 vv = *(float4*)&eps[r*ES + c4*4];
      int grow = rb + wr*64 + mf*16 + r;
      int gcol = cb + wn*(NF*16) + c4*4;
      if (EPI == 1){
        ushort4 u;
        u.x = f2bf(vv.x); u.y = f2bf(vv.y); u.z = f2bf(vv.z); u.w = f2bf(vv.w);
        *(ushort4*)&((ushort*)Cv)[(size_t)grow*N + gcol] = u;
      } else if (EPI == 2){
        if (grow < Mreal){
          float* cp = &((float*)Cv)[(size_t)grow*N + gcol];
          float4 o = *(float4*)cp;
          o.x += vv.x; o.y += vv.y; o.z += vv.z; o.w += vv.w;
          *(float4*)cp = o;
        }
      } else { // EPI == 3
        if (grow < Mreal){
          int bn = grow / 196, sp = grow - bn*196;
          float4 pv = *(const float4*)&pos[(size_t)(1+sp)*HID + gcol];
          vv.x += pv.x; vv.y += pv.y; vv.z += pv.z; vv.w += pv.w;
          *(float4*)&((float*)Cv)[((size_t)bn*SEQ + 1 + sp)*HID + gcol] = vv;
        }
      }
    }
  }
}

// ---------------- LayerNorm (fp32 in, bf16 out), float4 vectorized ---------
__global__ __launch_bounds__(128)
void ln_kernel(const float* __restrict__ x, const float* __restrict__ g,
               const float* __restrict__ b, ushort* __restrict__ y){
  int tok = blockIdx.x, t = threadIdx.x;
  int wave = t >> 6;
  __shared__ float red[2];
  float4 v = *(const float4*)&x[(size_t)tok*HID + t*4];
  float s = (v.x + v.y) + (v.z + v.w);
  #pragma unroll
  for (int off = 32; off; off >>= 1) s += __shfl_xor(s, off);
  if ((t & 63) == 0) red[wave] = s;
  __syncthreads();
  float mean = (red[0] + red[1]) * (1.0f/512.0f);
  __syncthreads();
  float dx = v.x - mean, dy = v.y - mean, dz = v.z - mean, dw = v.w - mean;
  s = (dx*dx + dy*dy) + (dz*dz + dw*dw);
  #pragma unroll
  for (int off = 32; off; off >>= 1) s += __shfl_xor(s, off);
  if ((t & 63) == 0) red[wave] = s;
  __syncthreads();
  float var = (red[0] + red[1]) * (1.0f/512.0f);
  float rs  = rsqrtf(var + 1e-5f);
  float4 gv = *(const float4*)&g[t*4];
  float4 bv = *(const float4*)&b[t*4];
  ushort4 o;
  o.x = f2bf(dx*rs*gv.x + bv.x);
  o.y = f2bf(dy*rs*gv.y + bv.y);
  o.z = f2bf(dz*rs*gv.z + bv.z);
  o.w = f2bf(dw*rs*gv.w + bv.w);
  *(ushort4*)&y[(size_t)tok*HID + t*4] = o;
}

// ---------------- MFMA QKV projection, fused q/k/v per block -------------
// grid (M2/128, 8): block stages y[128][hh*64..] once, computes all three
// projections for head hh (3x MFMA amortization per A-load, y traffic /3).
__global__ __launch_bounds__(256)
void qkv_mfma(const ushort* __restrict__ y,
              const ushort* __restrict__ wqb, const ushort* __restrict__ wkb,
              const ushort* __restrict__ wvb,
              const float* __restrict__ bq, const float* __restrict__ bk,
              const float* __restrict__ bv,
              ushort* __restrict__ q, ushort* __restrict__ k,
              ushort* __restrict__ v){
  __shared__ short As[128*64];       // 16 KB
  __shared__ short Bs[3][64*64];     // 24 KB
  int t = threadIdx.x;
  int lane = t & 63, wave = t >> 6;
  int l16 = lane & 15, g = lane >> 4;
  int hh = blockIdx.y;
  int rb = blockIdx.x * 128;

  const ushort* Wp[3] = { wqb + (size_t)hh*64*64, wkb + (size_t)hh*64*64, wvb + (size_t)hh*64*64 };
  const float* biasp[3] = { bq + hh*64, bk + hh*64, bv + hh*64 };
  ushort* outp[3] = { q, k, v };

  int srow = t >> 3, skoff = (t & 7) * 8;
  const ushort* Ab = y + (size_t)(rb + srow)*HID + hh*64 + skoff;
  #pragma unroll
  for (int i = 0; i < 4; ++i)
    gld_lds16(Ab + (size_t)(i*32)*HID, (ushort*)&As[t*8 + i*2048]);
  #pragma unroll
  for (int p = 0; p < 3; ++p){
    const ushort* Bb = Wp[p] + (size_t)srow*64 + skoff;
    #pragma unroll
    for (int i = 0; i < 2; ++i)
      gld_lds16(Bb + (size_t)(i*32)*64, (ushort*)&Bs[p][t*8 + i*2048]);
  }
  __syncthreads();

  // A fragments to registers first (frees As for epilogue staging)
  bf16x8 af[2][2];
  #pragma unroll
  for (int kc = 0; kc < 2; ++kc)
    #pragma unroll
    for (int m = 0; m < 2; ++m)
      af[kc][m] = *(bf16x8*)&As[(wave*32 + m*16 + l16)*64 + kc*32 + g*8];
  __syncthreads();   // all waves have read As; safe to reuse as staging

  ushort* eps = (ushort*)As + wave*(16*72);
  #pragma unroll
  for (int p = 0; p < 3; ++p){
    f32x4 acc[2][4];
    #pragma unroll
    for (int m = 0; m < 2; ++m)
      #pragma unroll
      for (int n = 0; n < 4; ++n)
        acc[m][n] = (f32x4){0.f,0.f,0.f,0.f};
    #pragma unroll
    for (int kc = 0; kc < 2; ++kc){
      bf16x8 bfr[4];
      #pragma unroll
      for (int n = 0; n < 4; ++n)
        bfr[n] = *(bf16x8*)&Bs[p][(n*16 + l16)*64 + kc*32 + g*8];
      #pragma unroll
      for (int m = 0; m < 2; ++m)
        #pragma unroll
        for (int n = 0; n < 4; ++n)
          acc[m][n] = __builtin_amdgcn_mfma_f32_16x16x32_bf16(af[kc][m], bfr[n], acc[m][n], 0, 0, 0);
    }
    float bvv[4];
    #pragma unroll
    for (int nd = 0; nd < 4; ++nd) bvv[nd] = biasp[p][nd*16 + l16];
    ushort* out = outp[p];
    #pragma unroll
    for (int mch = 0; mch < 2; ++mch){
      #pragma unroll
      for (int nd = 0; nd < 4; ++nd)
        #pragma unroll
        for (int j = 0; j < 4; ++j)
          eps[(g*4+j)*72 + nd*16 + l16] = f2bf(acc[mch][nd][j] + bvv[nd]);
      #pragma unroll
      for (int i = 0; i < 2; ++i){
        int id = i*64 + lane;
        int r = id >> 3, c8 = id & 7;
        uint4 vv = *(uint4*)&eps[r*72 + c8*8];
        int tok = rb + wave*32 + mch*16 + r;
        if (tok < TT)
          *(uint4*)&out[(size_t)tok*HID + hh*64 + c8*8] = vv;
      }
    }
  }
}

// ---------------- MFMA flash attention + residual add into h ----------------
__global__ __launch_bounds__(512, 4)
void attn_kernel(const ushort* __restrict__ q, const ushort* __restrict__ k,
                 const ushort* __restrict__ v, float* __restrict__ h){
  __shared__ ushort Ks[SPAD*64];
  __shared__ ushort Vs[64*256];
  __shared__ ushort Ps[8][32*40];
  int nh = blockIdx.x;
  int n = nh >> 3, hd = nh & 7;
  int t = threadIdx.x;
  int lane = t & 63, wave = t >> 6;
  int l16 = lane & 15, g = lane >> 4;

  const ushort* kbase = k + ((size_t)n*SEQ)*HID + hd*64;
  for (int c = t; c < 224*8; c += 512){
    int s = c >> 3, c8 = (c & 7) * 8;
    int sr = s < SEQ ? s : SEQ-1;
    uint4 val = *(const uint4*)&kbase[(size_t)sr*HID + c8];
    int byte = s*128 + c8*2;
    byte ^= (s & 7) << 4;
    *(uint4*)((char*)Ks + byte) = val;
  }
  const ushort* vbase = v + ((size_t)n*SEQ)*HID + hd*64;
  for (int c = t; c < 224*8; c += 512){
    int s = c >> 3, d8 = (c & 7) * 8;
    uint4 val = {0u,0u,0u,0u};
    if (s < SEQ) val = *(const uint4*)&vbase[(size_t)s*HID + d8];
    ushort* vsp = (ushort*)Vs;
    #pragma unroll
    for (int e = 0; e < 8; ++e){
      int d = d8 + e;
      int swzi = ((d & 7) ^ ((d >> 3) & 7)) << 4;
      int byte = d*512 + ((s*2) ^ swzi);
      vsp[byte >> 1] = ((ushort*)&val)[e];
    }
  }

  int qrow0 = wave * 32;
  bool wactive = qrow0 < SEQ;
  bf16x8 aq[2][2];
  if (wactive){
    #pragma unroll
    for (int m = 0; m < 2; ++m){
      int row = qrow0 + m*16 + l16;
      int sr = row < SEQ ? row : SEQ-1;
      const ushort* qp = q + ((size_t)n*SEQ + sr)*HID + hd*64;
      #pragma unroll
      for (int kc = 0; kc < 2; ++kc)
        aq[m][kc] = *(const bf16x8*)&qp[kc*32 + g*8];
    }
  }
  __syncthreads();

  if (wactive){
    ushort* myP = &Ps[wave][0];
    f32x4 accO[2][4];
    float mrun[2][4], lrun[2][4];
    #pragma unroll
    for (int m = 0; m < 2; ++m){
      #pragma unroll
      for (int nd = 0; nd < 4; ++nd) accO[m][nd] = (f32x4){0.f,0.f,0.f,0.f};
      #pragma unroll
      for (int j = 0; j < 4; ++j){ mrun[m][j] = -1e30f; lrun[m][j] = 0.f; }
    }

    for (int kt = 0; kt < 7; ++kt){
      f32x4 accS[2][2];
      #pragma unroll
      for (int m = 0; m < 2; ++m)
        #pragma unroll
        for (int nn = 0; nn < 2; ++nn) accS[m][nn] = (f32x4){0.f,0.f,0.f,0.f};
      #pragma unroll
      for (int kc = 0; kc < 2; ++kc){
        bf16x8 bk[2];
        #pragma unroll
        for (int nn = 0; nn < 2; ++nn){
          int srow = kt*32 + nn*16 + l16;
          int byte = srow*128 + kc*64 + g*16;
          byte ^= (srow & 7) << 4;
          bk[nn] = *(const bf16x8*)((const char*)Ks + byte);
        }
        #pragma unroll
        for (int m = 0; m < 2; ++m)
          #pragma unroll
          for (int nn = 0; nn < 2; ++nn)
            accS[m][nn] = __builtin_amdgcn_mfma_f32_16x16x32_bf16(aq[m][kc], bk[nn], accS[m][nn], 0, 0, 0);
      }
      bool kv0 = (kt*32 + l16) < SEQ;
      bool kv1 = (kt*32 + 16 + l16) < SEQ;
      #pragma unroll
      for (int m = 0; m < 2; ++m){
        #pragma unroll
        for (int j = 0; j < 4; ++j){
          float s0 = kv0 ? accS[m][0][j]*0.125f : -1e30f;
          float s1 = kv1 ? accS[m][1][j]*0.125f : -1e30f;
          float mx = fmaxf(s0, s1);
          mx = fmaxf(mx, __shfl_xor(mx, 1));
          mx = fmaxf(mx, __shfl_xor(mx, 2));
          mx = fmaxf(mx, __shfl_xor(mx, 4));
          mx = fmaxf(mx, __shfl_xor(mx, 8));
          float mold = mrun[m][j];
          float mnew = fmaxf(mold, mx);
          float corr = __expf(mold - mnew);
          mrun[m][j] = mnew;
          float p0 = __expf(s0 - mnew);
          float p1 = __expf(s1 - mnew);
          float rs = p0 + p1;
          rs += __shfl_xor(rs, 1);
          rs += __shfl_xor(rs, 2);
          rs += __shfl_xor(rs, 4);
          rs += __shfl_xor(rs, 8);
          lrun[m][j] = lrun[m][j]*corr + rs;
          #pragma unroll
          for (int nd = 0; nd < 4; ++nd) accO[m][nd][j] *= corr;
          int prow = m*16 + g*4 + j;
          myP[prow*40 + l16]      = f2bf(p0);
          myP[prow*40 + 16 + l16] = f2bf(p1);
        }
      }
      bf16x8 ap[2], bv[4];
      #pragma unroll
      for (int m = 0; m < 2; ++m)
        ap[m] = *(const bf16x8*)&myP[(m*16 + l16)*40 + g*8];
      #pragma unroll
      for (int nd = 0; nd < 4; ++nd){
        int d = nd*16 + l16;
        int byte = d*512 + kt*64 + g*16;
        byte ^= ((d & 7) ^ ((d >> 3) & 7)) << 4;
        bv[nd] = *(const bf16x8*)((const char*)Vs + byte);
      }
      #pragma unroll
      for (int m = 0; m < 2; ++m)
        #pragma unroll
        for (int nd = 0; nd < 4; ++nd)
          accO[m][nd] = __builtin_amdgcn_mfma_f32_16x16x32_bf16(ap[m], bv[nd], accO[m][nd], 0, 0, 0);
    }

    #pragma unroll
    for (int m = 0; m < 2; ++m){
      #pragma unroll
      for (int j = 0; j < 4; ++j){
        int row = qrow0 + m*16 + g*4 + j;
        if (row < SEQ){
          float inv = 1.0f / lrun[m][j];
          float* hp = h + ((size_t)n*SEQ + row)*HID + hd*64;
          #pragma unroll
          for (int nd = 0; nd < 4; ++nd)
            hp[nd*16 + l16] += accO[m][nd][j] * inv;
        }
      }
    }
  }
}

// ---------------- head stage 1: logits ----------------
__global__ __launch_bounds__(256)
void head_logits(const float* __restrict__ h, const float* __restrict__ W,
                 const float* __restrict__ b, float* __restrict__ logits){
  int c0 = blockIdx.x * 8;
  __shared__ float Ws[512*8];
  int t = threadIdx.x;
  for (int i = t; i < 512*8; i += 256){
    int kx = i >> 3, c = i & 7;
    Ws[i] = W[(size_t)kx*OUTC + c0 + c];
  }
  __syncthreads();
  int n = t >> 2, g = t & 3;
  const float* hp = h + (size_t)n*SEQ*HID + g*128;
  float acc[8] = {};
  for (int kx = 0; kx < 128; ++kx){
    float hv = hp[kx];
    const float* wsr = &Ws[(g*128 + kx)*8];
    #pragma unroll
    for (int c = 0; c < 8; ++c) acc[c] += hv * wsr[c];
  }
  #pragma unroll
  for (int c = 0; c < 8; ++c){
    acc[c] += __shfl_xor(acc[c], 1);
    acc[c] += __shfl_xor(acc[c], 2);
  }
  if (g == 0){
    #pragma unroll
    for (int c = 0; c < 8; ++c)
      logits[(size_t)n*OUTC + c0 + c] = acc[c] + b[c0 + c];
  }
}

// ---------------- head stage 2: softmax ----------------
__global__ __launch_bounds__(256)
void head_softmax(const float* __restrict__ logits, float* __restrict__ out){
  int n = blockIdx.x, t = threadIdx.x;
  __shared__ float red[4];
  float v[4];
  #pragma unroll
  for (int j = 0; j < 4; ++j){
    int e = t + j*256;
    v[j] = (e < OUTC) ? logits[(size_t)n*OUTC + e] : -1e30f;
  }
  float mx = fmaxf(fmaxf(v[0], v[1]), fmaxf(v[2], v[3]));
  #pragma unroll
  for (int off = 32; off; off >>= 1) mx = fmaxf(mx, __shfl_xor(mx, off));
  if ((t & 63) == 0) red[t >> 6] = mx;
  __syncthreads();
  mx = fmaxf(fmaxf(red[0], red[1]), fmaxf(red[2], red[3]));
  __syncthreads();
  float sum = 0.f;
  #pragma unroll
  for (int j = 0; j < 4; ++j){ v[j] = __expf(v[j] - mx); sum += v[j]; }
  #pragma unroll
  for (int off = 32; off; off >>= 1) sum += __shfl_xor(sum, off);
  if ((t & 63) == 0) red[t >> 6] = sum;
  __syncthreads();
  sum = red[0] + red[1] + red[2] + red[3];
  float inv = 1.0f / sum;
  #pragma unroll
  for (int j = 0; j < 4; ++j){
    int e = t + j*256;
    if (e < OUTC) out[(size_t)n*OUTC + e] = v[j] * inv;
  }
}

extern "C" void kernel_launch(void* const* d_in, const int* in_sizes, int n_in,
                              void* d_out, int out_size, void* d_ws, size_t ws_size,
                              hipStream_t stream){
  const float* x       = (const float*)d_in[0];
  const float* embed_W = (const float*)d_in[1];
  const float* embed_b = (const float*)d_in[2];
  const float* cls     = (const float*)d_in[3];
  const float* ln1_g   = (const float*)d_in[4];
  const float* ln1_b   = (const float*)d_in[5];
  const float* qW      = (const float*)d_in[6];
  const float* qb      = (const float*)d_in[7];
  const float* kW      = (const float*)d_in[8];
  const float* kb      = (const float*)d_in[9];
  const float* vW      = (const float*)d_in[10];
  const float* vb      = (const float*)d_in[11];
  const float* ln2_g   = (const float*)d_in[12];
  const float* ln2_b   = (const float*)d_in[13];
  const float* mlp1_W  = (const float*)d_in[14];
  const float* mlp1_b  = (const float*)d_in[15];
  const float* mlp2_W  = (const float*)d_in[16];
  const float* mlp2_b  = (const float*)d_in[17];
  const float* head_W  = (const float*)d_in[18];
  const float* head_b  = (const float*)d_in[19];
  float* out = (float*)d_out;

  char* wsb = (char*)d_ws;
  float*  h   = (float*)wsb;                                   // M2*512 f32
  ushort* y   = (ushort*)(wsb + (size_t)M2*HID*4);             // M2*512 bf16
  float*  logits = (float*)y;                                  // reuse post-loop
  char*   un  = wsb + (size_t)M2*HID*4 + (size_t)M2*HID*2;     // union region
  ushort* qb_  = (ushort*)un;                                  // TT*512 bf16
  ushort* kb_  = qb_ + (size_t)TT*HID;
  ushort* vb_  = kb_ + (size_t)TT*HID;
  ushort* z1  = (ushort*)un;                                   // M2*2048 bf16
  ushort* p   = (ushort*)un;                                   // patches (pre-loop)
  char*   wts = un + (size_t)3*TT*HID*4;
  ushort* w1t = (ushort*)wts;
  ushort* w2t = w1t + (size_t)LAY*2048*512;
  ushort* wet = w2t + (size_t)LAY*2048*512;
  ushort* wqb = wet + (size_t)IN_DIM*HID;
  ushort* wkb = wqb + (size_t)LAY*NH*DH*DH;
  ushort* wvb = wkb + (size_t)LAY*NH*DH*DH;
  float*  pos = (float*)(wvb + (size_t)LAY*NH*DH*DH);          // SEQ*HID f32

  pos_kernel<<<SEQ, 512, 0, stream>>>(pos);
  convt_kernel<<<dim3(2048/32, 512/32, LAY), 256, 0, stream>>>(mlp1_W, w1t, 512, 2048);
  convt_kernel<<<dim3(512/32, 2048/32, LAY), 256, 0, stream>>>(mlp2_W, w2t, 2048, 512);
  convt_kernel<<<dim3(512/32, 768/32, 1),    256, 0, stream>>>(embed_W, wet, 768, 512);
  {
    int cnt = LAY*NH*DH*DH;
    int grd = (cnt + 255)/256;
    cvt_kernel<<<grd, 256, 0, stream>>>(qW, wqb, cnt);
    cvt_kernel<<<grd, 256, 0, stream>>>(kW, wkb, cnt);
    cvt_kernel<<<grd, 256, 0, stream>>>(vW, wvb, cnt);
  }

  patchify_kernel<<<(NPTOK*IN_DIM)/256, 256, 0, stream>>>(x, p);
  cls_kernel<<<BATCH, 512, 0, stream>>>(cls, pos, h);
  gemm_pipe<128, 3><<<(512/128)*(M2/128), 256, 0, stream>>>(
      p, wet, embed_b, h, IN_DIM, HID, NPTOK, 512/128, pos);

  for (int l = 0; l < LAY; ++l){
    ln_kernel<<<TT, 128, 0, stream>>>(h, ln1_g + l*HID, ln1_b + l*HID, y);
    qkv_mfma<<<dim3(M2/128, 8), 256, 0, stream>>>(
        y,
        wqb + (size_t)l*NH*DH*DH, wkb + (size_t)l*NH*DH*DH, wvb + (size_t)l*NH*DH*DH,
        qb + (size_t)l*HID, kb + (size_t)l*HID, vb + (size_t)l*HID,
        qb_, kb_, vb_);
    attn_kernel<<<BATCH*NH, 512, 0, stream>>>(qb_, kb_, vb_, h);
    ln_kernel<<<TT, 128, 0, stream>>>(h, ln2_g + l*HID, ln2_b + l*HID, y);
    gemm_pipe<128, 1><<<(2048/128)*(M2/128), 256, 0, stream>>>(
        y, w1t + (size_t)l*2048*512, mlp1_b + (size_t)l*4*HID, z1,
        HID, 4*HID, TT, 2048/128, pos);
    gemm_pipe<128, 2><<<(512/128)*(M2/128), 256, 0, stream>>>(
        z1, w2t + (size_t)l*2048*512, mlp2_b + (size_t)l*HID, h,
        4*HID, HID, TT, 512/128, pos);
  }

  head_logits<<<125, 256, 0, stream>>>(h, head_W, head_b, logits);
  head_softmax<<<BATCH, 256, 0, stream>>>(logits, out);
}